// Round 1
// baseline (299.495 us; speedup 1.0000x reference)
//
#include <hip/hip_runtime.h>
#include <math.h>

#define HH 256
#define WW 256
#define CC 64
#define NB 8

// ---------------------------------------------------------------------------
// Kernel 1: Mt[c*64 + k] = M[k][c],  M = softmax(G,rows) @ P @ softmax(A,rows)
// Single block, 1024 threads, runs on one CU (~4 us). Tiny vs main kernel.
// ---------------------------------------------------------------------------
__global__ __launch_bounds__(1024) void prep_M(const float* __restrict__ A,
                                               const float* __restrict__ G,
                                               const float* __restrict__ P,
                                               float* __restrict__ Mt) {
    __shared__ __align__(16) float As[64][68];
    __shared__ __align__(16) float Gs[64][68];
    __shared__ __align__(16) float T[64][68];

    const int t = threadIdx.x;
    const int wave = t >> 6;
    const int lane = t & 63;

    // Row softmax for A (rows 0..63) and G (rows 64..127): 16 waves x 8 rows.
    for (int r8 = 0; r8 < 8; ++r8) {
        int row = wave * 8 + r8;       // 0..127
        int r = row & 63;
        const float* src = (row < 64) ? A : G;
        float v = src[r * 64 + lane];
        float m = v;
        #pragma unroll
        for (int off = 32; off > 0; off >>= 1)
            m = fmaxf(m, __shfl_xor(m, off, 64));
        float e = __expf(v - m);
        float s = e;
        #pragma unroll
        for (int off = 32; off > 0; off >>= 1)
            s += __shfl_xor(s, off, 64);
        float o = e / s;
        if (row < 64) As[r][lane] = o; else Gs[r][lane] = o;
    }
    __syncthreads();

    // T = P @ As   (T[d][c] = sum_e P[d][e] * As[e][c])
    {
        const int d = t >> 4, q = t & 15;
        float4 acc = make_float4(0.f, 0.f, 0.f, 0.f);
        for (int e = 0; e < 64; ++e) {
            float p = P[d * 64 + e];
            float4 a = *(const float4*)&As[e][4 * q];
            acc.x = fmaf(p, a.x, acc.x);
            acc.y = fmaf(p, a.y, acc.y);
            acc.z = fmaf(p, a.z, acc.z);
            acc.w = fmaf(p, a.w, acc.w);
        }
        *(float4*)&T[d][4 * q] = acc;
    }
    __syncthreads();

    // M = Gs @ T ; write transposed: Mt[c*64 + k] = M[k][c]
    {
        const int k = t >> 4, q = t & 15;
        float4 acc = make_float4(0.f, 0.f, 0.f, 0.f);
        for (int d = 0; d < 64; ++d) {
            float g = Gs[k][d];
            float4 tv = *(const float4*)&T[d][4 * q];
            acc.x = fmaf(g, tv.x, acc.x);
            acc.y = fmaf(g, tv.y, acc.y);
            acc.z = fmaf(g, tv.z, acc.z);
            acc.w = fmaf(g, tv.w, acc.w);
        }
        Mt[(4 * q + 0) * 64 + k] = acc.x;
        Mt[(4 * q + 1) * 64 + k] = acc.y;
        Mt[(4 * q + 2) * 64 + k] = acc.z;
        Mt[(4 * q + 3) * 64 + k] = acc.w;
    }
}

// ---------------------------------------------------------------------------
// Kernel 2: fused depthwise 3x3 conv + 64x64 channel mix.
// Block = (one batch b, one row h, 64-pixel w-tile) x all 64 channels.
// Phase 1: thread (c = t>>2, chunk = t&3) computes 16 conv outputs -> LDS.
// Phase 2: thread (ki = t>>4, wj = t&15) computes 4k x 4w output tile.
// ---------------------------------------------------------------------------
__global__ __launch_bounds__(256) void fused_conv_mix(const float* __restrict__ x,
                                                      const float* __restrict__ dwgt,
                                                      const float* __restrict__ Mt,
                                                      float* __restrict__ out) {
    __shared__ __align__(16) float MtS[64][68];  // MtS[c][k] = M[k][c]
    __shared__ __align__(16) float dwS[64][68];  // dwS[c][w_local]

    const int t = threadIdx.x;
    const int tw0 = blockIdx.x * 64;
    const int h = blockIdx.y;
    const int b = blockIdx.z;

    // Stage Mt -> LDS (4096 floats, 4 float4 per thread), before the barrier.
    {
        #pragma unroll
        for (int j = 0; j < 4; ++j) {
            int idx = (j * 256 + t) * 4;       // float index, multiple of 4
            int row = idx >> 6;
            int col = idx & 63;
            float4 v = *(const float4*)(Mt + idx);
            *(float4*)&MtS[row][col] = v;
        }
    }

    // ---- Phase 1: depthwise conv, 16 outputs per thread ----
    {
        const int c = t >> 2;
        const int chunk = t & 3;
        const int gw0 = tw0 + chunk * 16;      // first output w of this thread
        const float* xc = x + ((size_t)(b * CC + c) * HH) * WW;

        float r[3][18];
        #pragma unroll
        for (int dy = 0; dy < 3; ++dy) {
            int y = h + dy - 1;
            if ((unsigned)y < (unsigned)HH) {
                const float* p = xc + y * WW + gw0;
                const float4* p4 = (const float4*)p;
                float4 v0 = p4[0], v1 = p4[1], v2 = p4[2], v3 = p4[3];
                r[dy][1] = v0.x;  r[dy][2] = v0.y;  r[dy][3] = v0.z;  r[dy][4] = v0.w;
                r[dy][5] = v1.x;  r[dy][6] = v1.y;  r[dy][7] = v1.z;  r[dy][8] = v1.w;
                r[dy][9] = v2.x;  r[dy][10] = v2.y; r[dy][11] = v2.z; r[dy][12] = v2.w;
                r[dy][13] = v3.x; r[dy][14] = v3.y; r[dy][15] = v3.z; r[dy][16] = v3.w;
                r[dy][0]  = (gw0 > 0)        ? p[-1] : 0.f;
                r[dy][17] = (gw0 + 16 < WW)  ? p[16] : 0.f;
            } else {
                #pragma unroll
                for (int i = 0; i < 18; ++i) r[dy][i] = 0.f;
            }
        }

        float wg[9];
        #pragma unroll
        for (int i = 0; i < 9; ++i) wg[i] = dwgt[c * 9 + i];

        float acc[16];
        #pragma unroll
        for (int i = 0; i < 16; ++i) {
            float a = 0.f;
            #pragma unroll
            for (int dy = 0; dy < 3; ++dy)
                #pragma unroll
                for (int dx = 0; dx < 3; ++dx)
                    a = fmaf(wg[dy * 3 + dx], r[dy][i + dx], a);
            acc[i] = a;
        }

        // dwS[c][chunk*16 .. chunk*16+15]
        #pragma unroll
        for (int v = 0; v < 4; ++v) {
            float4 w4 = make_float4(acc[4 * v + 0], acc[4 * v + 1],
                                    acc[4 * v + 2], acc[4 * v + 3]);
            *(float4*)&dwS[c][chunk * 16 + 4 * v] = w4;
        }
    }

    __syncthreads();

    // ---- Phase 2: channel mix, 4x4 register tile per thread ----
    {
        const int ki = t >> 4;   // k rows 4*ki .. 4*ki+3
        const int wj = t & 15;   // w cols 4*wj .. 4*wj+3
        float o00 = 0.f, o01 = 0.f, o02 = 0.f, o03 = 0.f;
        float o10 = 0.f, o11 = 0.f, o12 = 0.f, o13 = 0.f;
        float o20 = 0.f, o21 = 0.f, o22 = 0.f, o23 = 0.f;
        float o30 = 0.f, o31 = 0.f, o32 = 0.f, o33 = 0.f;

        #pragma unroll 4
        for (int c = 0; c < 64; ++c) {
            float4 m = *(const float4*)&MtS[c][4 * ki];
            float4 d = *(const float4*)&dwS[c][4 * wj];
            o00 = fmaf(m.x, d.x, o00); o01 = fmaf(m.x, d.y, o01);
            o02 = fmaf(m.x, d.z, o02); o03 = fmaf(m.x, d.w, o03);
            o10 = fmaf(m.y, d.x, o10); o11 = fmaf(m.y, d.y, o11);
            o12 = fmaf(m.y, d.z, o12); o13 = fmaf(m.y, d.w, o13);
            o20 = fmaf(m.z, d.x, o20); o21 = fmaf(m.z, d.y, o21);
            o22 = fmaf(m.z, d.z, o22); o23 = fmaf(m.z, d.w, o23);
            o30 = fmaf(m.w, d.x, o30); o31 = fmaf(m.w, d.y, o31);
            o32 = fmaf(m.w, d.z, o32); o33 = fmaf(m.w, d.w, o33);
        }

        float* ob = out + ((size_t)(b * CC) * HH + h) * WW + tw0 + 4 * wj;
        const size_t kstride = (size_t)HH * WW;
        {
            int k = 4 * ki;
            *(float4*)(ob + (size_t)(k + 0) * kstride) = make_float4(o00, o01, o02, o03);
            *(float4*)(ob + (size_t)(k + 1) * kstride) = make_float4(o10, o11, o12, o13);
            *(float4*)(ob + (size_t)(k + 2) * kstride) = make_float4(o20, o21, o22, o23);
            *(float4*)(ob + (size_t)(k + 3) * kstride) = make_float4(o30, o31, o32, o33);
        }
    }
}

extern "C" void kernel_launch(void* const* d_in, const int* in_sizes, int n_in,
                              void* d_out, int out_size, void* d_ws, size_t ws_size,
                              hipStream_t stream) {
    const float* x    = (const float*)d_in[0];  // [8,64,256,256]
    const float* dwgt = (const float*)d_in[1];  // [64,1,3,3]
    const float* pwgt = (const float*)d_in[2];  // [64,64,1,1]
    const float* attw = (const float*)d_in[3];  // [64,64]
    const float* gatt = (const float*)d_in[4];  // [64,64]
    float* Mt = (float*)d_ws;                   // 4096 floats
    float* o  = (float*)d_out;

    prep_M<<<1, 1024, 0, stream>>>(attw, gatt, pwgt, Mt);

    dim3 grid(WW / 64, HH, NB);
    fused_conv_mix<<<grid, 256, 0, stream>>>(x, dwgt, Mt, o);
}

// Round 3
// 287.201 us; speedup vs baseline: 1.0428x; 1.0428x over previous
//
#include <hip/hip_runtime.h>
#include <math.h>

#define HH 256
#define WW 256
#define CC 64
#define NB 8
#define ROWS 8

typedef float fvec4 __attribute__((ext_vector_type(4)));

// ---------------------------------------------------------------------------
// Kernel 1: Mt[c*64 + k] = M[k][c],  M = softmax(G,rows) @ P @ softmax(A,rows)
// ---------------------------------------------------------------------------
__global__ __launch_bounds__(1024) void prep_M(const float* __restrict__ A,
                                               const float* __restrict__ G,
                                               const float* __restrict__ P,
                                               float* __restrict__ Mt) {
    __shared__ __align__(16) float As[64][68];
    __shared__ __align__(16) float Gs[64][68];
    __shared__ __align__(16) float T[64][68];

    const int t = threadIdx.x;
    const int wave = t >> 6;
    const int lane = t & 63;

    for (int r8 = 0; r8 < 8; ++r8) {
        int row = wave * 8 + r8;       // 0..127
        int r = row & 63;
        const float* src = (row < 64) ? A : G;
        float v = src[r * 64 + lane];
        float m = v;
        #pragma unroll
        for (int off = 32; off > 0; off >>= 1)
            m = fmaxf(m, __shfl_xor(m, off, 64));
        float e = __expf(v - m);
        float s = e;
        #pragma unroll
        for (int off = 32; off > 0; off >>= 1)
            s += __shfl_xor(s, off, 64);
        float o = e / s;
        if (row < 64) As[r][lane] = o; else Gs[r][lane] = o;
    }
    __syncthreads();

    // T = P @ As
    {
        const int d = t >> 4, q = t & 15;
        float4 acc = make_float4(0.f, 0.f, 0.f, 0.f);
        for (int e = 0; e < 64; ++e) {
            float p = P[d * 64 + e];
            float4 a = *(const float4*)&As[e][4 * q];
            acc.x = fmaf(p, a.x, acc.x);
            acc.y = fmaf(p, a.y, acc.y);
            acc.z = fmaf(p, a.z, acc.z);
            acc.w = fmaf(p, a.w, acc.w);
        }
        *(float4*)&T[d][4 * q] = acc;
    }
    __syncthreads();

    // M = Gs @ T ; store transposed
    {
        const int k = t >> 4, q = t & 15;
        float4 acc = make_float4(0.f, 0.f, 0.f, 0.f);
        for (int d = 0; d < 64; ++d) {
            float g = Gs[k][d];
            float4 tv = *(const float4*)&T[d][4 * q];
            acc.x = fmaf(g, tv.x, acc.x);
            acc.y = fmaf(g, tv.y, acc.y);
            acc.z = fmaf(g, tv.z, acc.z);
            acc.w = fmaf(g, tv.w, acc.w);
        }
        Mt[(4 * q + 0) * 64 + k] = acc.x;
        Mt[(4 * q + 1) * 64 + k] = acc.y;
        Mt[(4 * q + 2) * 64 + k] = acc.z;
        Mt[(4 * q + 3) * 64 + k] = acc.w;
    }
}

// ---------------------------------------------------------------------------
// Kernel 2: strip-mined fused depthwise conv + channel mix.
// Block = (64-w tile, 8-row strip, batch). Rolling x rows in registers,
// Mt staged once, dwS double-buffered, one barrier per row, prefetch depth 1.
// ---------------------------------------------------------------------------
__global__ __launch_bounds__(256, 3) void fused_conv_mix(const float* __restrict__ x,
                                                         const float* __restrict__ dwgt,
                                                         const float* __restrict__ Mt,
                                                         float* __restrict__ out) {
    __shared__ __align__(16) float MtS[64][64];     // MtS[c][k] = M[k][c]
    __shared__ __align__(16) float dwS[2][64][68];  // double-buffered conv rows

    const int t = threadIdx.x;
    const int tw0 = blockIdx.x * 64;
    const int h0 = blockIdx.y * ROWS;
    const int b = blockIdx.z;

    // Stage Mt -> LDS (contiguous float4 per thread: conflict-free).
    {
        const float4* m4 = (const float4*)Mt;
        float4* s4 = (float4*)&MtS[0][0];
        #pragma unroll
        for (int j = 0; j < 4; ++j) s4[j * 256 + t] = m4[j * 256 + t];
    }

    const int c = t >> 2;
    const int chunk = t & 3;
    const int gw0 = tw0 + chunk * 16;
    const float* xc = x + ((size_t)(b * CC + c) * HH) * WW;

    float wg[9];
    #pragma unroll
    for (int i = 0; i < 9; ++i) wg[i] = dwgt[c * 9 + i];

    float rm[18], r0[18], rp[18], rn[18];

    auto load_row = [&](float* r, int y) {
        if ((unsigned)y < (unsigned)HH) {
            const float* p = xc + y * WW + gw0;
            const float4* p4 = (const float4*)p;
            float4 v0 = p4[0], v1 = p4[1], v2 = p4[2], v3 = p4[3];
            r[1] = v0.x;  r[2] = v0.y;  r[3] = v0.z;  r[4] = v0.w;
            r[5] = v1.x;  r[6] = v1.y;  r[7] = v1.z;  r[8] = v1.w;
            r[9] = v2.x;  r[10] = v2.y; r[11] = v2.z; r[12] = v2.w;
            r[13] = v3.x; r[14] = v3.y; r[15] = v3.z; r[16] = v3.w;
            r[0]  = (gw0 > 0)       ? p[-1] : 0.f;
            r[17] = (gw0 + 16 < WW) ? p[16] : 0.f;
        } else {
            #pragma unroll
            for (int i = 0; i < 18; ++i) r[i] = 0.f;
        }
    };

    load_row(rm, h0 - 1);
    load_row(r0, h0);
    load_row(rp, h0 + 1);

    __syncthreads();   // MtS ready

    const int ki = t >> 4;
    const int wj = t & 15;
    const size_t kstride = (size_t)HH * WW;

    #pragma unroll 1
    for (int i = 0; i < ROWS; ++i) {
        // ---- conv row h0+i -> dwS[i&1] ----
        {
            #pragma unroll
            for (int v = 0; v < 4; ++v) {
                float4 o4;
                float* oo = (float*)&o4;
                #pragma unroll
                for (int u = 0; u < 4; ++u) {
                    int j = 4 * v + u;
                    float a = 0.f;
                    #pragma unroll
                    for (int dx = 0; dx < 3; ++dx) {
                        a = fmaf(wg[0 * 3 + dx], rm[j + dx], a);
                        a = fmaf(wg[1 * 3 + dx], r0[j + dx], a);
                        a = fmaf(wg[2 * 3 + dx], rp[j + dx], a);
                    }
                    oo[u] = a;
                }
                *(float4*)&dwS[i & 1][c][chunk * 16 + 4 * v] = o4;
            }
        }
        __syncthreads();

        // prefetch row h0+i+2 during the mix
        if (i < ROWS - 1) load_row(rn, h0 + i + 2);

        // ---- mix: out[k][h0+i][tw0+4wj..] = sum_c M[k][c] * dw[c][w] ----
        {
            float o00 = 0.f, o01 = 0.f, o02 = 0.f, o03 = 0.f;
            float o10 = 0.f, o11 = 0.f, o12 = 0.f, o13 = 0.f;
            float o20 = 0.f, o21 = 0.f, o22 = 0.f, o23 = 0.f;
            float o30 = 0.f, o31 = 0.f, o32 = 0.f, o33 = 0.f;

            #pragma unroll 4
            for (int cc2 = 0; cc2 < 64; ++cc2) {
                float4 m = *(const float4*)&MtS[cc2][4 * ki];
                float4 d = *(const float4*)&dwS[i & 1][cc2][4 * wj];
                o00 = fmaf(m.x, d.x, o00); o01 = fmaf(m.x, d.y, o01);
                o02 = fmaf(m.x, d.z, o02); o03 = fmaf(m.x, d.w, o03);
                o10 = fmaf(m.y, d.x, o10); o11 = fmaf(m.y, d.y, o11);
                o12 = fmaf(m.y, d.z, o12); o13 = fmaf(m.y, d.w, o13);
                o20 = fmaf(m.z, d.x, o20); o21 = fmaf(m.z, d.y, o21);
                o22 = fmaf(m.z, d.z, o22); o23 = fmaf(m.z, d.w, o23);
                o30 = fmaf(m.w, d.x, o30); o31 = fmaf(m.w, d.y, o31);
                o32 = fmaf(m.w, d.z, o32); o33 = fmaf(m.w, d.w, o33);
            }

            float* ob = out + ((size_t)(b * CC) * HH + (h0 + i)) * WW + tw0 + 4 * wj;
            const int k = 4 * ki;
            fvec4 s0 = {o00, o01, o02, o03};
            fvec4 s1 = {o10, o11, o12, o13};
            fvec4 s2 = {o20, o21, o22, o23};
            fvec4 s3 = {o30, o31, o32, o33};
            __builtin_nontemporal_store(s0, (fvec4*)(ob + (size_t)(k + 0) * kstride));
            __builtin_nontemporal_store(s1, (fvec4*)(ob + (size_t)(k + 1) * kstride));
            __builtin_nontemporal_store(s2, (fvec4*)(ob + (size_t)(k + 2) * kstride));
            __builtin_nontemporal_store(s3, (fvec4*)(ob + (size_t)(k + 3) * kstride));
        }

        // rotate rolling rows
        #pragma unroll
        for (int j = 0; j < 18; ++j) { rm[j] = r0[j]; r0[j] = rp[j]; rp[j] = rn[j]; }
    }
}

extern "C" void kernel_launch(void* const* d_in, const int* in_sizes, int n_in,
                              void* d_out, int out_size, void* d_ws, size_t ws_size,
                              hipStream_t stream) {
    const float* x    = (const float*)d_in[0];  // [8,64,256,256]
    const float* dwgt = (const float*)d_in[1];  // [64,1,3,3]
    const float* pwgt = (const float*)d_in[2];  // [64,64,1,1]
    const float* attw = (const float*)d_in[3];  // [64,64]
    const float* gatt = (const float*)d_in[4];  // [64,64]
    float* Mt = (float*)d_ws;                   // 4096 floats
    float* o  = (float*)d_out;

    prep_M<<<1, 1024, 0, stream>>>(attw, gatt, pwgt, Mt);

    dim3 grid(WW / 64, HH / ROWS, NB);
    fused_conv_mix<<<grid, 256, 0, stream>>>(x, dwgt, Mt, o);
}

// Round 4
// 257.766 us; speedup vs baseline: 1.1619x; 1.1142x over previous
//
#include <hip/hip_runtime.h>
#include <math.h>

#define HH 256
#define WW 256
#define CC 64
#define NB 8
#define ROWS 8

typedef float fvec4 __attribute__((ext_vector_type(4)));
typedef float floatx4 __attribute__((ext_vector_type(4)));
typedef _Float16 half8 __attribute__((ext_vector_type(8)));

// ---------------------------------------------------------------------------
// Kernel 1: Mh[k][c] = f16( softmax(G) @ P @ softmax(A) )[k][c], row-major.
// ---------------------------------------------------------------------------
__global__ __launch_bounds__(1024) void prep_M(const float* __restrict__ A,
                                               const float* __restrict__ G,
                                               const float* __restrict__ P,
                                               _Float16* __restrict__ Mh) {
    __shared__ __align__(16) float As[64][68];
    __shared__ __align__(16) float Gs[64][68];
    __shared__ __align__(16) float T[64][68];

    const int t = threadIdx.x;
    const int wave = t >> 6;
    const int lane = t & 63;

    for (int r8 = 0; r8 < 8; ++r8) {
        int row = wave * 8 + r8;       // 0..127
        int r = row & 63;
        const float* src = (row < 64) ? A : G;
        float v = src[r * 64 + lane];
        float m = v;
        #pragma unroll
        for (int off = 32; off > 0; off >>= 1)
            m = fmaxf(m, __shfl_xor(m, off, 64));
        float e = __expf(v - m);
        float s = e;
        #pragma unroll
        for (int off = 32; off > 0; off >>= 1)
            s += __shfl_xor(s, off, 64);
        float o = e / s;
        if (row < 64) As[r][lane] = o; else Gs[r][lane] = o;
    }
    __syncthreads();

    // T = P @ As
    {
        const int d = t >> 4, q = t & 15;
        float4 acc = make_float4(0.f, 0.f, 0.f, 0.f);
        for (int e = 0; e < 64; ++e) {
            float p = P[d * 64 + e];
            float4 a = *(const float4*)&As[e][4 * q];
            acc.x = fmaf(p, a.x, acc.x);
            acc.y = fmaf(p, a.y, acc.y);
            acc.z = fmaf(p, a.z, acc.z);
            acc.w = fmaf(p, a.w, acc.w);
        }
        *(float4*)&T[d][4 * q] = acc;
    }
    __syncthreads();

    // M = Gs @ T ; store f16 row-major: Mh[k*64 + c]
    {
        const int k = t >> 4, q = t & 15;
        float4 acc = make_float4(0.f, 0.f, 0.f, 0.f);
        for (int d = 0; d < 64; ++d) {
            float g = Gs[k][d];
            float4 tv = *(const float4*)&T[d][4 * q];
            acc.x = fmaf(g, tv.x, acc.x);
            acc.y = fmaf(g, tv.y, acc.y);
            acc.z = fmaf(g, tv.z, acc.z);
            acc.w = fmaf(g, tv.w, acc.w);
        }
        _Float16* mp = Mh + k * 64 + 4 * q;
        mp[0] = (_Float16)acc.x;
        mp[1] = (_Float16)acc.y;
        mp[2] = (_Float16)acc.z;
        mp[3] = (_Float16)acc.w;
    }
}

// ---------------------------------------------------------------------------
// Kernel 2: strip-mined fused depthwise conv (fp32 VALU) + channel mix
// via mfma_f32_16x16x32_f16. M lives in A-fragments in registers (no LDS);
// conv writes rows transposed dwT[w][c] so B-fragments are contiguous b128.
// One barrier per row; dwT double-buffered; prefetch depth 1 (3 rolling rows,
// full unroll renames registers).
// ---------------------------------------------------------------------------
__global__ __launch_bounds__(256, 4) void fused_conv_mix(const float* __restrict__ x,
                                                         const float* __restrict__ dwgt,
                                                         const _Float16* __restrict__ Mh,
                                                         float* __restrict__ out) {
    __shared__ __align__(16) float dwT[2][64][68];   // [buf][w_local][c], 34.8 KB

    const int t = threadIdx.x;
    const int tw0 = blockIdx.x * 64;
    const int h0 = blockIdx.y * ROWS;
    const int b = blockIdx.z;

    // ---- conv persona ----
    const int c = t >> 2;
    const int chunk = t & 3;
    const int gw0 = tw0 + chunk * 16;
    const float* xc = x + ((size_t)(b * CC + c) * HH) * WW;

    float wg[9];
    #pragma unroll
    for (int i = 0; i < 9; ++i) wg[i] = dwgt[c * 9 + i];

    // ---- mix persona ----
    const int wave = t >> 6;          // k-block = wave*16
    const int lane = t & 63;
    const int q = lane >> 4;          // quad
    const int mrow = lane & 15;       // A row (k within tile) / B col (w within subtile)

    // A-fragments: M[k = wave*16 + mrow][c = s*32 + q*8 + j], j=0..7. Held all kernel.
    half8 af0, af1;
    {
        const half8* ap = (const half8*)(Mh + (wave * 16 + mrow) * 64);
        af0 = ap[q];          // c0 = q*8
        af1 = ap[4 + q];      // c0 = 32 + q*8
    }

    float rows[3][18];

    auto load_row = [&](float* r, int y) {
        if ((unsigned)y < (unsigned)HH) {
            const float* p = xc + y * WW + gw0;
            const float4* p4 = (const float4*)p;
            float4 v0 = p4[0], v1 = p4[1], v2 = p4[2], v3 = p4[3];
            r[1] = v0.x;  r[2] = v0.y;  r[3] = v0.z;  r[4] = v0.w;
            r[5] = v1.x;  r[6] = v1.y;  r[7] = v1.z;  r[8] = v1.w;
            r[9] = v2.x;  r[10] = v2.y; r[11] = v2.z; r[12] = v2.w;
            r[13] = v3.x; r[14] = v3.y; r[15] = v3.z; r[16] = v3.w;
            r[0]  = (gw0 > 0)       ? p[-1] : 0.f;
            r[17] = (gw0 + 16 < WW) ? p[16] : 0.f;
        } else {
            #pragma unroll
            for (int i = 0; i < 18; ++i) r[i] = 0.f;
        }
    };

    load_row(rows[0], h0 - 1);
    load_row(rows[1], h0);
    load_row(rows[2], h0 + 1);

    const size_t kstride = (size_t)HH * WW;

    #pragma unroll
    for (int i = 0; i < ROWS; ++i) {
        const float* rm_ = rows[(i + 0) % 3];
        const float* r0_ = rows[(i + 1) % 3];
        const float* rp_ = rows[(i + 2) % 3];

        // ---- conv row h0+i -> dwT[i&1][w][c] (transposed) ----
        #pragma unroll
        for (int j = 0; j < 16; ++j) {
            float a = 0.f;
            #pragma unroll
            for (int dx = 0; dx < 3; ++dx) {
                a = fmaf(wg[0 * 3 + dx], rm_[j + dx], a);
                a = fmaf(wg[1 * 3 + dx], r0_[j + dx], a);
                a = fmaf(wg[2 * 3 + dx], rp_[j + dx], a);
            }
            dwT[i & 1][chunk * 16 + j][c] = a;
        }
        __syncthreads();

        // prefetch row h0+i+2 into the retiring buffer (register-renamed)
        if (i < ROWS - 1) load_row(rows[i % 3], h0 + i + 2);

        // ---- mix via MFMA: out[k][w] = sum_c M[k][c] * dw[c][w] ----
        {
            floatx4 dd[4];
            #pragma unroll
            for (int s = 0; s < 4; ++s) dd[s] = (floatx4){0.f, 0.f, 0.f, 0.f};

            #pragma unroll
            for (int sub = 0; sub < 4; ++sub) {
                const float* bp = &dwT[i & 1][sub * 16 + mrow][q * 8];
                fvec4 alo = *(const fvec4*)(bp);
                fvec4 ahi = *(const fvec4*)(bp + 4);
                fvec4 blo = *(const fvec4*)(bp + 32);
                fvec4 bhi = *(const fvec4*)(bp + 36);
                half8 hb0, hb1;
                #pragma unroll
                for (int j = 0; j < 4; ++j) {
                    hb0[j]     = (_Float16)alo[j];
                    hb0[j + 4] = (_Float16)ahi[j];
                    hb1[j]     = (_Float16)blo[j];
                    hb1[j + 4] = (_Float16)bhi[j];
                }
                dd[sub] = __builtin_amdgcn_mfma_f32_16x16x32_f16(af0, hb0, dd[sub], 0, 0, 0);
                dd[sub] = __builtin_amdgcn_mfma_f32_16x16x32_f16(af1, hb1, dd[sub], 0, 0, 0);
            }

            // D layout: col(w) = lane&15, row(k) = q*4 + reg
            float* obase = out + (((size_t)(b * CC + wave * 16 + q * 4)) * HH + (h0 + i)) * WW + tw0;
            #pragma unroll
            for (int r = 0; r < 4; ++r) {
                float* orow = obase + (size_t)r * kstride + mrow;
                #pragma unroll
                for (int sub = 0; sub < 4; ++sub)
                    __builtin_nontemporal_store(dd[sub][r], orow + sub * 16);
            }
        }
    }
}

extern "C" void kernel_launch(void* const* d_in, const int* in_sizes, int n_in,
                              void* d_out, int out_size, void* d_ws, size_t ws_size,
                              hipStream_t stream) {
    const float* x    = (const float*)d_in[0];  // [8,64,256,256]
    const float* dwgt = (const float*)d_in[1];  // [64,1,3,3]
    const float* pwgt = (const float*)d_in[2];  // [64,64,1,1]
    const float* attw = (const float*)d_in[3];  // [64,64]
    const float* gatt = (const float*)d_in[4];  // [64,64]
    _Float16* Mh = (_Float16*)d_ws;             // 4096 f16 = 8 KB
    float* o  = (float*)d_out;

    prep_M<<<1, 1024, 0, stream>>>(attw, gatt, pwgt, Mh);

    dim3 grid(WW / 64, HH / ROWS, NB);
    fused_conv_mix<<<grid, 256, 0, stream>>>(x, dwgt, Mh, o);
}